// Round 2
// baseline (4389.450 us; speedup 1.0000x reference)
//
#include <hip/hip_runtime.h>

#define K1 3072
#define N1 1024
#define NCOL 50
#define BM 256
#define BN 128
#define BK 32
#define NSTEP (K1 / BK)   // 96
#define SAS 40            // staging row stride (bf16 elems) = 80 B, 16B-aligned
#define SHS 136           // h / w2t row stride = 272 B, 16B-aligned

typedef float  f32x4  __attribute__((ext_vector_type(4)));
typedef short  short8 __attribute__((ext_vector_type(8)));

struct __align__(16) Smem {
  union {
    struct { short A[2][BM * SAS]; short BT[2][BN * SAS]; } s;  // 61.4 KB staging (dbuf)
    short h[128 * SHS];                                          // 34.8 KB epilogue
  } u;
  short w2t[64 * SHS];                                           // 17.4 KB
};

__device__ inline unsigned bfr(float f) {           // round-half-up bf16 bits in lo16
  return (__builtin_bit_cast(unsigned, f) + 0x8000u) >> 16;
}
__device__ inline short f2bf(float f) { return (short)bfr(f); }
__device__ inline short8 cvt8(float4 a, float4 b) {
  short8 r;
  r[0] = f2bf(a.x); r[1] = f2bf(a.y); r[2] = f2bf(a.z); r[3] = f2bf(a.w);
  r[4] = f2bf(b.x); r[5] = f2bf(b.y); r[6] = f2bf(b.z); r[7] = f2bf(b.w);
  return r;
}

__global__ __launch_bounds__(256, 2)
void hoi_fused(const float* __restrict__ X, const float* __restrict__ W1,
               const float* __restrict__ B1, const float* __restrict__ W2,
               const float* __restrict__ B2, float* __restrict__ OUT) {
  __shared__ Smem sm;
  const int tid  = threadIdx.x;
  const int lane = tid & 63, wid = tid >> 6;
  const int l15  = lane & 15, g = lane >> 4;

  // XCD-grouped swizzle: 8 consecutive blocks on one XCD share the same m-panel
  const int bid   = blockIdx.x;
  const int xcd   = bid & 7, o = bid >> 3;
  const int m_blk = xcd * 16 + (o >> 3);   // 0..127
  const int n_blk = o & 7;                  // 0..7
  const int m0 = m_blk * BM, n0 = n_blk * BN;

  // ---- staging assignments ----
  // A: thread covers rows {ar + 64p}, k-cols akc..akc+7 (coalesced: 4 lanes/row x 32B)
  const int ar  = tid >> 2;            // 0..63
  const int akc = (tid & 3) * 8;       // 0,8,16,24
  const float* aptr = X + (size_t)(m0 + ar) * K1 + akc;
  // B: thread covers k-rows {2*bk2, 2*bk2+1}, cols {bcm + 16i} (write-bank-friendly)
  const int bk2 = tid >> 4;            // 0..15
  const int bcm = tid & 15;            // 0..15
  const float* bptr = W1 + (size_t)(2 * bk2) * N1 + n0 + bcm;

  f32x4 acc[4][8] = {};
  float4 ra[8];
  float  rb0[8], rb1[8];

  // prologue: load tile 0
#pragma unroll
  for (int p = 0; p < 4; ++p) {
    const float* ap = aptr + (size_t)p * 64 * K1;
    ra[2 * p]     = *(const float4*)(ap);
    ra[2 * p + 1] = *(const float4*)(ap + 4);
  }
#pragma unroll
  for (int i = 0; i < 8; ++i) { rb0[i] = bptr[16 * i]; rb1[i] = bptr[N1 + 16 * i]; }

  int cur = 0;
  for (int step = 0; step < NSTEP; ++step) {
    // ---- write staged regs -> LDS[cur] (bf16) ----
#pragma unroll
    for (int p = 0; p < 4; ++p)
      *(short8*)&sm.u.s.A[cur][(ar + 64 * p) * SAS + akc] = cvt8(ra[2 * p], ra[2 * p + 1]);
#pragma unroll
    for (int i = 0; i < 8; ++i) {
      unsigned pk = bfr(rb0[i]) |
                    ((__builtin_bit_cast(unsigned, rb1[i]) + 0x8000u) & 0xFFFF0000u);
      *(unsigned*)&sm.u.s.BT[cur][(bcm + 16 * i) * SAS + 2 * bk2] = pk;
    }

    // ---- issue next tile's global loads (latency hidden under barrier+MFMA) ----
    if (step + 1 < NSTEP) {
      const int k0 = (step + 1) * BK;
#pragma unroll
      for (int p = 0; p < 4; ++p) {
        const float* ap = aptr + (size_t)p * 64 * K1 + k0;
        ra[2 * p]     = *(const float4*)(ap);
        ra[2 * p + 1] = *(const float4*)(ap + 4);
      }
      const float* bp = bptr + (size_t)k0 * N1;
#pragma unroll
      for (int i = 0; i < 8; ++i) { rb0[i] = bp[16 * i]; rb1[i] = bp[N1 + 16 * i]; }
    }

    __syncthreads();   // tile staged; t+1 writes go to the other buffer (no 2nd barrier)

    // ---- MFMA: wave owns rows wid*64..+63, all 128 cols ----
    short8 af[4];
#pragma unroll
    for (int mt = 0; mt < 4; ++mt)
      af[mt] = *(const short8*)&sm.u.s.A[cur][(wid * 64 + mt * 16 + l15) * SAS + g * 8];
#pragma unroll
    for (int nt = 0; nt < 8; ++nt) {
      short8 bfv = *(const short8*)&sm.u.s.BT[cur][(nt * 16 + l15) * SAS + g * 8];
#pragma unroll
      for (int mt = 0; mt < 4; ++mt)
        acc[mt][nt] = __builtin_amdgcn_mfma_f32_16x16x32_bf16(af[mt], bfv, acc[mt][nt], 0, 0, 0);
    }
    cur ^= 1;
  }

  // ---- epilogue: bias+relu -> h (bf16 LDS), then GEMM2, two 128-row phases ----
  float b1v[8];
#pragma unroll
  for (int nt = 0; nt < 8; ++nt) b1v[nt] = B1[n0 + nt * 16 + l15];

  const int mh_w = wid >> 1;   // phase in which this wave writes its h rows

  for (int mh = 0; mh < 2; ++mh) {
    __syncthreads();   // prior phase reads done (and k-loop reads done for mh=0)

    if (mh_w == mh) {
      const int rbase = (wid & 1) * 64;
#pragma unroll
      for (int mt = 0; mt < 4; ++mt)
#pragma unroll
        for (int nt = 0; nt < 8; ++nt) {
          const int ntp = (nt + g) & 7;          // bank stagger: 2-way free
          const int c = ntp * 16 + l15;
#pragma unroll
          for (int j = 0; j < 4; ++j) {
            const int r = rbase + mt * 16 + g * 4 + j;
            sm.u.h[r * SHS + c] = f2bf(fmaxf(acc[mt][ntp][j] + b1v[ntp], 0.f));
          }
        }
    }
    if (mh == 0) {   // stage w2 slice transposed: w2t[c][kk] = W2[n0+kk][c]
      const int kk = tid >> 1, ch = (tid & 1) * 32;
#pragma unroll
      for (int i = 0; i < 32; ++i) {
        const int c = ch + i;
        const float v = (c < NCOL) ? W2[(size_t)(n0 + kk) * NCOL + c] : 0.f;
        sm.w2t[c * SHS + kk] = f2bf(v);
      }
    }
    __syncthreads();

    // GEMM2: 128 rows x 50 cols, k = BN = 128; wave takes 32 rows
    f32x4 acc2[2][4] = {};
#pragma unroll
    for (int ks = 0; ks < 4; ++ks) {
      short8 a2f[2];
#pragma unroll
      for (int mt2 = 0; mt2 < 2; ++mt2)
        a2f[mt2] = *(const short8*)&sm.u.h[(wid * 32 + mt2 * 16 + l15) * SHS + ks * 32 + g * 8];
#pragma unroll
      for (int nt2 = 0; nt2 < 4; ++nt2) {
        short8 b2f = *(const short8*)&sm.w2t[(nt2 * 16 + l15) * SHS + ks * 32 + g * 8];
#pragma unroll
        for (int mt2 = 0; mt2 < 2; ++mt2)
          acc2[mt2][nt2] = __builtin_amdgcn_mfma_f32_16x16x32_bf16(a2f[mt2], b2f, acc2[mt2][nt2], 0, 0, 0);
      }
    }

#pragma unroll
    for (int mt2 = 0; mt2 < 2; ++mt2)
#pragma unroll
      for (int nt2 = 0; nt2 < 4; ++nt2) {
        const int c = nt2 * 16 + l15;
        if (c < NCOL) {
#pragma unroll
          for (int j = 0; j < 4; ++j) {
            const int r = m0 + mh * 128 + wid * 32 + mt2 * 16 + g * 4 + j;
            float v = acc2[mt2][nt2][j];
            if (n_blk == 0) v += B2[c];
            atomicAdd(&OUT[(size_t)r * NCOL + c], v);
          }
        }
      }
  }
}

extern "C" void kernel_launch(void* const* d_in, const int* in_sizes, int n_in,
                              void* d_out, int out_size, void* d_ws, size_t ws_size,
                              hipStream_t stream) {
  const float* X  = (const float*)d_in[0];
  const float* W1 = (const float*)d_in[1];
  const float* B1 = (const float*)d_in[2];
  const float* W2 = (const float*)d_in[3];
  const float* B2 = (const float*)d_in[4];
  float* OUT = (float*)d_out;

  hipMemsetAsync(d_out, 0, (size_t)out_size * sizeof(float), stream);
  hipLaunchKernelGGL(hoi_fused, dim3(1024), dim3(256), 0, stream, X, W1, B1, W2, B2, OUT);
}

// Round 3
// 471.090 us; speedup vs baseline: 9.3176x; 9.3176x over previous
//
#include <hip/hip_runtime.h>

#define K1 3072
#define N1 1024
#define NCOL 50
#define BK 32
#define NSTEP (K1 / BK)   // 96
#define SAS 40            // staging row stride (bf16) = 80 B
#define SHS 136           // h / w2t row stride = 272 B

typedef float  f32x4  __attribute__((ext_vector_type(4)));
typedef short  short8 __attribute__((ext_vector_type(8)));

struct __align__(16) Smem {
  union {
    struct { short A[128 * SAS]; short BT[128 * SAS]; } s;  // 20.5 KB staging
    short h[64 * SHS];                                       // 17.4 KB epilogue
  } u;
  short w2t[64 * SHS];                                       // 17.4 KB (not aliased)
};  // ~37.9 KB

__device__ inline unsigned bfr(float f) {          // round-half-up bf16 bits in lo16
  return (__builtin_bit_cast(unsigned, f) + 0x8000u) >> 16;
}
__device__ inline short f2bf(float f) { return (short)bfr(f); }
__device__ inline short8 cvt8(float4 a, float4 b) {
  short8 r;
  r[0] = f2bf(a.x); r[1] = f2bf(a.y); r[2] = f2bf(a.z); r[3] = f2bf(a.w);
  r[4] = f2bf(b.x); r[5] = f2bf(b.y); r[6] = f2bf(b.z); r[7] = f2bf(b.w);
  return r;
}

__global__ __launch_bounds__(256, 2)
void hoi_fused(const float* __restrict__ X, const float* __restrict__ W1,
               const float* __restrict__ B1, const float* __restrict__ W2,
               const float* __restrict__ B2, float* __restrict__ OUT) {
  __shared__ Smem sm;
  const int tid  = threadIdx.x;
  const int lane = tid & 63, wid = tid >> 6;
  const int wr = wid >> 1, wc = wid & 1;
  const int l15 = lane & 15, g = lane >> 4;

  // XCD-grouped swizzle: the 8 n-blocks of one m-panel run consecutively on ONE XCD
  const int bid   = blockIdx.x;
  const int xcd   = bid & 7, o = bid >> 3;        // o in [0,256)
  const int m_blk = xcd * 32 + (o >> 3);          // 0..255
  const int n_blk = o & 7;                        // 0..7
  const int m0 = m_blk * 128, n0 = n_blk * 128;

  // ---- staging assignments ----
  // A: row = tid>>1 (0..127), k-chunk 16 floats at akc
  const int arow = tid >> 1;
  const int akc  = (tid & 1) << 4;                // 0 / 16
  const float* aptr = X + (size_t)(m0 + arow) * K1 + akc;
  // B: k-pair rows {2*bk2, 2*bk2+1}, cols bcm+16i (pack k-pairs -> b32 writes, 2-way free)
  const int bk2 = tid >> 4;                        // 0..15
  const int bcm = tid & 15;                        // 0..15
  const float* bptr = W1 + (size_t)(2 * bk2) * N1 + n0 + bcm;

  // ---- stage w2 slice transposed (non-aliased region), visible after first barrier ----
  {
    const int kk = tid >> 1, ch = (tid & 1) * 32;
#pragma unroll
    for (int i = 0; i < 32; ++i) {
      const int c = ch + i;
      const float v = (c < NCOL) ? W2[(size_t)(n0 + kk) * NCOL + c] : 0.f;
      sm.w2t[c * SHS + kk] = f2bf(v);
    }
  }

  // bias for this block's columns
  float b1v[4];
#pragma unroll
  for (int nt = 0; nt < 4; ++nt) b1v[nt] = B1[n0 + wc * 64 + nt * 16 + l15];

  f32x4 acc[4][4] = {};
  float4 ra[4];
  float  rb0[8], rb1[8];

  // prologue: tile 0 into regs
#pragma unroll
  for (int q = 0; q < 4; ++q) ra[q] = *(const float4*)(aptr + 4 * q);
#pragma unroll
  for (int i = 0; i < 8; ++i) { rb0[i] = bptr[16 * i]; rb1[i] = bptr[N1 + 16 * i]; }

  for (int step = 0; step < NSTEP; ++step) {
    __syncthreads();   // previous step's frag reads complete

    // A tile -> LDS (two b128 writes)
    *(short8*)&sm.u.s.A[arow * SAS + akc + 0] = cvt8(ra[0], ra[1]);
    *(short8*)&sm.u.s.A[arow * SAS + akc + 8] = cvt8(ra[2], ra[3]);
    // B^T tile -> LDS (eight b32 k-pair writes, banks (20*bcm+bk2): 2-way max)
#pragma unroll
    for (int i = 0; i < 8; ++i) {
      unsigned pk = bfr(rb0[i]) |
                    ((__builtin_bit_cast(unsigned, rb1[i]) + 0x8000u) & 0xFFFF0000u);
      *(unsigned*)&sm.u.s.BT[(bcm + 16 * i) * SAS + 2 * bk2] = pk;
    }

    // issue next tile's global loads (hidden under barrier + MFMA)
    if (step + 1 < NSTEP) {
      const int k0 = (step + 1) * BK;
#pragma unroll
      for (int q = 0; q < 4; ++q) ra[q] = *(const float4*)(aptr + k0 + 4 * q);
      const float* bp = bptr + (size_t)k0 * N1;
#pragma unroll
      for (int i = 0; i < 8; ++i) { rb0[i] = bp[16 * i]; rb1[i] = bp[N1 + 16 * i]; }
    }

    __syncthreads();   // tile staged

    short8 af[4];
#pragma unroll
    for (int mt = 0; mt < 4; ++mt)
      af[mt] = *(const short8*)&sm.u.s.A[(wr * 64 + mt * 16 + l15) * SAS + g * 8];
#pragma unroll
    for (int nt = 0; nt < 4; ++nt) {
      short8 bfv = *(const short8*)&sm.u.s.BT[(wc * 64 + nt * 16 + l15) * SAS + g * 8];
#pragma unroll
      for (int mt = 0; mt < 4; ++mt)
        acc[mt][nt] = __builtin_amdgcn_mfma_f32_16x16x32_bf16(af[mt], bfv, acc[mt][nt], 0, 0, 0);
    }
  }

  // ---- epilogue: two 64-row phases; h aliases the staging LDS ----
  for (int p = 0; p < 2; ++p) {
    __syncthreads();   // p=0: k-loop reads done; p=1: phase-0 GEMM2 reads done

    if (wr == p) {     // waves owning rows p*64..p*64+63 write bias+relu h (bf16)
#pragma unroll
      for (int mt = 0; mt < 4; ++mt)
#pragma unroll
        for (int nt = 0; nt < 4; ++nt) {
          const int c = wc * 64 + nt * 16 + l15;
#pragma unroll
          for (int j = 0; j < 4; ++j) {
            const int r = mt * 16 + g * 4 + j;   // local 0..63
            sm.u.h[r * SHS + c] = f2bf(fmaxf(acc[mt][nt][j] + b1v[nt], 0.f));
          }
        }
    }
    __syncthreads();   // h (and w2t, staged long ago) visible

    // GEMM2: 64 rows x 50 cols, K = 128; each wave takes 16 rows
    f32x4 acc2[4] = {};
#pragma unroll
    for (int ks = 0; ks < 4; ++ks) {
      const short8 a2f = *(const short8*)&sm.u.h[(wid * 16 + l15) * SHS + ks * 32 + g * 8];
#pragma unroll
      for (int nt2 = 0; nt2 < 4; ++nt2) {
        const short8 b2f = *(const short8*)&sm.w2t[(nt2 * 16 + l15) * SHS + ks * 32 + g * 8];
        acc2[nt2] = __builtin_amdgcn_mfma_f32_16x16x32_bf16(a2f, b2f, acc2[nt2], 0, 0, 0);
      }
    }

#pragma unroll
    for (int nt2 = 0; nt2 < 4; ++nt2) {
      const int c = nt2 * 16 + l15;
      if (c < NCOL) {
#pragma unroll
        for (int j = 0; j < 4; ++j) {
          const int r = m0 + p * 64 + wid * 16 + g * 4 + j;
          float v = acc2[nt2][j];
          if (n_blk == 0) v += B2[c];
          atomicAdd(&OUT[(size_t)r * NCOL + c], v);
        }
      }
    }
  }
}

extern "C" void kernel_launch(void* const* d_in, const int* in_sizes, int n_in,
                              void* d_out, int out_size, void* d_ws, size_t ws_size,
                              hipStream_t stream) {
  const float* X  = (const float*)d_in[0];
  const float* W1 = (const float*)d_in[1];
  const float* B1 = (const float*)d_in[2];
  const float* W2 = (const float*)d_in[3];
  const float* B2 = (const float*)d_in[4];
  float* OUT = (float*)d_out;

  hipMemsetAsync(d_out, 0, (size_t)out_size * sizeof(float), stream);
  hipLaunchKernelGGL(hoi_fused, dim3(2048), dim3(256), 0, stream, X, W1, B1, W2, B2, OUT);
}